// Round 3
// baseline (311.975 us; speedup 1.0000x reference)
//
#include <hip/hip_runtime.h>
#include <hip/hip_bf16.h>
#include <stdint.h>

// Problem constants (fixed by the reference setup_inputs)
#define BATCH  16384
#define D_IN   1024
#define M_HID  4096
#define R_LORA 16
#define SCALING 2.0f   // ALPHA/R = 32/16

// GEMM tiling: 256x128 block tile, BK=64, 512 threads (8 waves: 4 row x 2 col),
// each wave computes 64x64 via 2x2 grid of mfma_f32_32x32x16_bf16.
// R2 post-mortem: 128x128/16x16x32 plateaued at 667 TF (MfmaUtil 29%) — short
// K-loop (16 iters) under-amortizes per-block fixed cost. Bigger tile halves
// block count; 32x32x16 MFMA gives 4060 vs 3378 FLOP/cyc.
#define BM 256
#define BN 128
#define BK 64
#define NTHREADS 512

typedef __bf16 bf16x8 __attribute__((ext_vector_type(8)));
typedef float  f32x16 __attribute__((ext_vector_type(16)));

// LDS layout: [row][slot], slot = chunk ^ (row&7), chunk = 8 shorts (16B).
// Keeps global_load_lds write path linear (lane-contiguous) while making
// fragment reads conflict-free (R2: SQ_LDS_BANK_CONFLICT 5e7 -> 0).

__device__ __forceinline__ unsigned short f2bf(float f) {
    union { float f; unsigned int u; } c; c.f = f;
    unsigned int u = c.u;
    return (unsigned short)((u + 0x7FFFu + ((u >> 16) & 1u)) >> 16);
}

// ---------------- fused prep kernel (1 launch) ----------------
#define PREP_X_BLOCKS   (BATCH * D_IN / 8 / 256)      // 8192
#define PREP_W_BLOCKS   (M_HID * D_IN / 4 / 256)      // 4096
#define PREP_O_BLOCKS   (BATCH / 256)                 // 64
__global__ __launch_bounds__(256) void k_prep(
    const float* __restrict__ x, const float* __restrict__ W0,
    const float* __restrict__ A, const float* __restrict__ Bl,
    const float* __restrict__ b2,
    unsigned short* __restrict__ xb, unsigned short* __restrict__ wb,
    float* __restrict__ out)
{
    int bid = blockIdx.x;
    if (bid < PREP_X_BLOCKS) {
        int idx = bid * 256 + threadIdx.x;
        const float4* x4 = (const float4*)x;
        float4 a = x4[2 * idx], b = x4[2 * idx + 1];
        uint4 o;
        o.x = (unsigned)f2bf(a.x) | ((unsigned)f2bf(a.y) << 16);
        o.y = (unsigned)f2bf(a.z) | ((unsigned)f2bf(a.w) << 16);
        o.z = (unsigned)f2bf(b.x) | ((unsigned)f2bf(b.y) << 16);
        o.w = (unsigned)f2bf(b.z) | ((unsigned)f2bf(b.w) << 16);
        ((uint4*)xb)[idx] = o;
    } else if (bid < PREP_X_BLOCKS + PREP_W_BLOCKS) {
        int idx = (bid - PREP_X_BLOCKS) * 256 + threadIdx.x;
        int m  = idx >> 8;
        int d4 = idx & 255;
        float4 acc = ((const float4*)W0)[idx];
        const float* brow = Bl + m * R_LORA;
#pragma unroll
        for (int r = 0; r < R_LORA; ++r) {
            float s = SCALING * brow[r];
            float4 a4 = ((const float4*)(A + r * D_IN))[d4];
            acc.x += s * a4.x; acc.y += s * a4.y; acc.z += s * a4.z; acc.w += s * a4.w;
        }
        uint2 o;
        o.x = (unsigned)f2bf(acc.x) | ((unsigned)f2bf(acc.y) << 16);
        o.y = (unsigned)f2bf(acc.z) | ((unsigned)f2bf(acc.w) << 16);
        ((uint2*)wb)[idx] = o;
    } else {
        int i = (bid - PREP_X_BLOCKS - PREP_W_BLOCKS) * 256 + threadIdx.x;
        out[i] = b2[0];
    }
}

__global__ __launch_bounds__(256) void k_init_out(float* __restrict__ out,
                                                  const float* __restrict__ b2) {
    out[blockIdx.x * 256 + threadIdx.x] = b2[0];
}

// ---------------- fused GEMM + epilogue ----------------
// FAST: xb/wb bf16 staged in ws (global_load_lds). else: convert in staging.
template<bool FAST>
__global__ __launch_bounds__(NTHREADS) void k_gemm_fused(
    const unsigned short* __restrict__ xb, const float* __restrict__ xf,
    const unsigned short* __restrict__ wb,
    const float* __restrict__ W0, const float* __restrict__ A,
    const float* __restrict__ Bl,
    const float* __restrict__ b0, const float* __restrict__ W2,
    float* __restrict__ out)
{
    __shared__ unsigned short As[BM * BK];   // 32 KiB
    __shared__ unsigned short Bs[BN * BK];   // 16 KiB

    const int tid  = threadIdx.x;
    const int lane = tid & 63;
    const int wave = tid >> 6;
    const int col0 = blockIdx.x * BN;        // hid dim (fast-varying -> x-tile L2 reuse)
    const int row0 = blockIdx.y * BM;        // batch dim
    const int wm = (wave & 3) * 64;          // wave row offset in 256-tile
    const int wn = (wave >> 2) * 64;         // wave col offset in 128-tile
    const int rl   = lane & 31;              // row/col lane within 32
    const int half = lane >> 5;

    f32x16 acc[2][2] = {};                   // 64 AGPRs

    for (int k0 = 0; k0 < D_IN; k0 += BK) {
        if (FAST) {
            // A tile: 256 rows x 8 chunks = 2048 chunks, 512 thr -> 4 iters
#pragma unroll
            for (int it = 0; it < 4; ++it) {
                int c = it * NTHREADS + tid;
                int r = c >> 3, s = c & 7;
                int k = s ^ (r & 7);
                const unsigned short* g = xb + (row0 + r) * D_IN + k0 + k * 8;
                __builtin_amdgcn_global_load_lds(
                    (__attribute__((address_space(1))) void*)g,
                    (__attribute__((address_space(3))) void*)(&As[c * 8]),
                    16, 0, 0);
            }
            // B tile: 128 rows x 8 chunks = 1024 chunks -> 2 iters
#pragma unroll
            for (int it = 0; it < 2; ++it) {
                int c = it * NTHREADS + tid;
                int r = c >> 3, s = c & 7;
                int k = s ^ (r & 7);
                const unsigned short* g = wb + (col0 + r) * D_IN + k0 + k * 8;
                __builtin_amdgcn_global_load_lds(
                    (__attribute__((address_space(1))) void*)g,
                    (__attribute__((address_space(3))) void*)(&Bs[c * 8]),
                    16, 0, 0);
            }
        } else {
            // A: 256x64 elems / 512 thr = 32 elems = 8 float4 loads
#pragma unroll
            for (int it = 0; it < 8; ++it) {
                int gidx = it * NTHREADS + tid;       // quad id: 256 rows x 16 quads
                int r = gidx >> 4, kc = (gidx & 15) * 4;
                float4 v = *(const float4*)(xf + (size_t)(row0 + r) * D_IN + k0 + kc);
                ushort4 o = make_ushort4(f2bf(v.x), f2bf(v.y), f2bf(v.z), f2bf(v.w));
                int k = kc >> 3, h4 = (gidx & 1) * 4;
                *(ushort4*)(&As[r * BK + ((k ^ (r & 7)) * 8) + h4]) = o;
            }
            // B: 128x64 elems / 512 thr = 16 elems = 4 float4 loads, LoRA fused
#pragma unroll
            for (int it = 0; it < 4; ++it) {
                int gidx = it * NTHREADS + tid;       // 128 rows x 16 quads
                int n = gidx >> 4, kc = (gidx & 15) * 4;
                float4 v = *(const float4*)(W0 + (size_t)(col0 + n) * D_IN + k0 + kc);
                const float* brow = Bl + (col0 + n) * R_LORA;
#pragma unroll
                for (int r = 0; r < R_LORA; ++r) {
                    float s = SCALING * brow[r];
                    float4 a4 = *(const float4*)(A + r * D_IN + k0 + kc);
                    v.x += s * a4.x; v.y += s * a4.y; v.z += s * a4.z; v.w += s * a4.w;
                }
                ushort4 o = make_ushort4(f2bf(v.x), f2bf(v.y), f2bf(v.z), f2bf(v.w));
                int k = kc >> 3, h4 = (gidx & 1) * 4;
                *(ushort4*)(&Bs[n * BK + ((k ^ (n & 7)) * 8) + h4]) = o;
            }
        }
        __syncthreads();   // drains vmcnt for global_load_lds too

        // ---- compute: 4 kk-steps(16) x 4 MFMA(32x32x16) ----
        // A/B frag: m(or n) = lane&31, k = (lane>>5)*8 + j
#pragma unroll
        for (int kk = 0; kk < BK; kk += 16) {
            const int chunk = (kk >> 3) + half;
            const int slot  = chunk ^ (rl & 7);       // row&7 == rl&7 (offsets mult of 32)
            bf16x8 af[2], bfr[2];
#pragma unroll
            for (int t = 0; t < 2; ++t)
                af[t] = *(const bf16x8*)(&As[(wm + t * 32 + rl) * BK + slot * 8]);
#pragma unroll
            for (int t = 0; t < 2; ++t)
                bfr[t] = *(const bf16x8*)(&Bs[(wn + t * 32 + rl) * BK + slot * 8]);
#pragma unroll
            for (int ti = 0; ti < 2; ++ti)
#pragma unroll
                for (int tj = 0; tj < 2; ++tj)
                    acc[ti][tj] = __builtin_amdgcn_mfma_f32_32x32x16_bf16(
                        af[ti], bfr[tj], acc[ti][tj], 0, 0, 0);
        }
        __syncthreads();
    }

    // ---- epilogue: relu(acc + b0)*W2, reduce over wave's 64 hid cols ----
    // C/D layout (m74/m101): col = lane&31, row = (reg&3) + 8*(reg>>2) + 4*half
    const int hid0 = col0 + wn + rl;
    const float w2a = W2[hid0],      bba = b0[hid0];
    const float w2b = W2[hid0 + 32], bbb = b0[hid0 + 32];
#pragma unroll
    for (int ti = 0; ti < 2; ++ti) {
#pragma unroll
        for (int r = 0; r < 16; ++r) {
            float p = fmaxf(acc[ti][0][r] + bba, 0.f) * w2a
                    + fmaxf(acc[ti][1][r] + bbb, 0.f) * w2b;
#pragma unroll
            for (int m = 1; m <= 16; m <<= 1)
                p += __shfl_xor(p, m, 64);
            if (rl == 0) {
                int row = row0 + wm + ti * 32 + (r & 3) + 8 * (r >> 2) + 4 * half;
                unsafeAtomicAdd(&out[row], p);
            }
        }
    }
}

// ---------------- host ----------------
extern "C" void kernel_launch(void* const* d_in, const int* in_sizes, int n_in,
                              void* d_out, int out_size, void* d_ws, size_t ws_size,
                              hipStream_t stream) {
    const float* x  = (const float*)d_in[0];
    const float* W0 = (const float*)d_in[1];
    const float* b0 = (const float*)d_in[2];
    const float* A  = (const float*)d_in[3];
    const float* Bl = (const float*)d_in[4];
    const float* W2 = (const float*)d_in[5];
    const float* b2 = (const float*)d_in[6];
    float* out = (float*)d_out;

    const size_t wb_bytes = (size_t)M_HID * D_IN * 2;   // 8 MiB
    const size_t xb_bytes = (size_t)BATCH * D_IN * 2;   // 32 MiB
    const bool have_ws = ws_size >= wb_bytes + xb_bytes;
    unsigned short* wb = (unsigned short*)d_ws;
    unsigned short* xb = (unsigned short*)((char*)d_ws + wb_bytes);

    dim3 grid(M_HID / BN, BATCH / BM);   // 32 x 64; col-block fastest -> x-tile L2 reuse

    if (have_ws) {
        hipLaunchKernelGGL(k_prep, dim3(PREP_X_BLOCKS + PREP_W_BLOCKS + PREP_O_BLOCKS),
                           dim3(256), 0, stream, x, W0, A, Bl, b2, xb, wb, out);
        hipLaunchKernelGGL((k_gemm_fused<true>), grid, dim3(NTHREADS), 0, stream,
                           xb, x, wb, W0, A, Bl, b0, W2, out);
    } else {
        hipLaunchKernelGGL(k_init_out, dim3(PREP_O_BLOCKS), dim3(256), 0, stream, out, b2);
        hipLaunchKernelGGL((k_gemm_fused<false>), grid, dim3(NTHREADS), 0, stream,
                           xb, x, wb, W0, A, Bl, b0, W2, out);
    }
}

// Round 4
// 259.889 us; speedup vs baseline: 1.2004x; 1.2004x over previous
//
#include <hip/hip_runtime.h>
#include <hip/hip_bf16.h>
#include <stdint.h>

// Problem constants (fixed by the reference setup_inputs)
#define BATCH  16384
#define D_IN   1024
#define M_HID  4096
#define R_LORA 16
#define SCALING 2.0f   // ALPHA/R = 32/16

// Structure (R4): barrier-free K-loop. One block per 64-row x-strip (256 blocks
// = 1/CU), x strip resident in LDS (128 KiB). 8 waves each sweep 8 chunks of
// 64 W-cols over full K=1024; W_eff comes global->VGPR from a fragment-ordered
// ws buffer (coalesced 1 KiB/instr), double-buffered in registers. No
// __syncthreads in the K-loop => no vmcnt(0) drain (the m97-structure stall).
#define STRIP    64
#define NTHREADS 512
#define KCH      (D_IN / 8)          // 128 16B-chunks per row

typedef __bf16 bf16x8 __attribute__((ext_vector_type(8)));
typedef float  f32x16 __attribute__((ext_vector_type(16)));

__device__ __forceinline__ unsigned short f2bf(float f) {
    union { float f; unsigned int u; } c; c.f = f;
    unsigned int u = c.u;
    return (unsigned short)((u + 0x7FFFu + ((u >> 16) & 1u)) >> 16);
}

// ---------------- prep: W_eff -> fragment-ordered bf16 ----------------
// Element (n32, c, rl) at short-offset n32*32768 + c*256 + rl*8 holds
// W_eff[n32*32+rl][c*8 .. c*8+8). A wave's B-fragment read (both halves) is
// then one contiguous 1 KiB global_load_dwordx4. id == linear offset/8.
__global__ __launch_bounds__(256) void k_wprep(
    const float* __restrict__ W0, const float* __restrict__ A,
    const float* __restrict__ Bl, unsigned short* __restrict__ wb)
{
    int id = blockIdx.x * 256 + threadIdx.x;        // 524288 total
    int rl  = id & 31;
    int c   = (id >> 5) & 127;
    int n32 = id >> 12;
    int n = n32 * 32 + rl, k0 = c * 8;
    const float* wr = W0 + (size_t)n * D_IN + k0;
    float4 v0 = *(const float4*)(wr);
    float4 v1 = *(const float4*)(wr + 4);
    const float* brow = Bl + n * R_LORA;
#pragma unroll
    for (int r = 0; r < R_LORA; ++r) {
        float s = SCALING * brow[r];
        const float* ar = A + r * D_IN + k0;
        float4 a0 = *(const float4*)(ar);
        float4 a1 = *(const float4*)(ar + 4);
        v0.x += s * a0.x; v0.y += s * a0.y; v0.z += s * a0.z; v0.w += s * a0.w;
        v1.x += s * a1.x; v1.y += s * a1.y; v1.z += s * a1.z; v1.w += s * a1.w;
    }
    uint4 o;
    o.x = (unsigned)f2bf(v0.x) | ((unsigned)f2bf(v0.y) << 16);
    o.y = (unsigned)f2bf(v0.z) | ((unsigned)f2bf(v0.w) << 16);
    o.z = (unsigned)f2bf(v1.x) | ((unsigned)f2bf(v1.y) << 16);
    o.w = (unsigned)f2bf(v1.z) | ((unsigned)f2bf(v1.w) << 16);
    ((uint4*)wb)[id] = o;
}

// ---------------- main fused kernel ----------------
__global__ __launch_bounds__(NTHREADS, 2) void k_strip(
    const float* __restrict__ xf, const unsigned short* __restrict__ wb,
    const float* __restrict__ b0, const float* __restrict__ W2,
    const float* __restrict__ b2, float* __restrict__ out)
{
    // x strip, [row][chunk-slot]; slot = (c & ~7) | ((c ^ r) & 7) (bank swizzle)
    __shared__ unsigned short As[STRIP * D_IN];   // 128 KiB
    __shared__ float red[8][STRIP];               // 2 KiB cross-wave reduce

    const int tid  = threadIdx.x;
    const int lane = tid & 63;
    const int wave = tid >> 6;
    const int rl   = lane & 31;
    const int half = lane >> 5;
    const int row0 = blockIdx.x * STRIP;

    // ---- phase 1: x fp32 -> bf16 into resident LDS strip ----
    {
        const int r  = tid >> 3;                  // 0..63
        const int c0 = tid & 7;
        const float* xr = xf + (size_t)(row0 + r) * D_IN;
        const int slo = (c0 ^ r) & 7;
#pragma unroll
        for (int i = 0; i < 16; ++i) {
            int c = i * 8 + c0;
            float4 v0 = *(const float4*)(xr + c * 8);
            float4 v1 = *(const float4*)(xr + c * 8 + 4);
            uint4 o;
            o.x = (unsigned)f2bf(v0.x) | ((unsigned)f2bf(v0.y) << 16);
            o.y = (unsigned)f2bf(v0.z) | ((unsigned)f2bf(v0.w) << 16);
            o.z = (unsigned)f2bf(v1.x) | ((unsigned)f2bf(v1.y) << 16);
            o.w = (unsigned)f2bf(v1.z) | ((unsigned)f2bf(v1.w) << 16);
            int slot = i * 8 + slo;
            *(uint4*)(&As[r * D_IN + slot * 8]) = o;
        }
    }
    __syncthreads();   // the only barrier before the final reduce

    float rowpart[2][16];
#pragma unroll
    for (int ti = 0; ti < 2; ++ti)
#pragma unroll
        for (int r = 0; r < 16; ++r) rowpart[ti][r] = 0.f;

    // ---- main: 8 passes x (K-loop with zero barriers) ----
    for (int pass = 0; pass < 8; ++pass) {
        const int n0 = wave * 64 + pass * 512;
        const float w2a = W2[n0 + rl],      b0a = b0[n0 + rl];
        const float w2b = W2[n0 + 32 + rl], b0b = b0[n0 + 32 + rl];
        const int n32 = wave * 2 + pass * 16;
        const unsigned short* w0p = wb + (size_t)n32 * 32768 + half * 256 + rl * 8;
        const unsigned short* w1p = w0p + 32768;

        f32x16 acc[2][2] = {};
        bf16x8 wf0[2], wf1[2];
        wf0[0] = *(const bf16x8*)(w0p);
        wf1[0] = *(const bf16x8*)(w1p);

#pragma unroll 4
        for (int kk = 0; kk < 64; ++kk) {
            const int cur = kk & 1, nxt = cur ^ 1;
            if (kk < 63) {                        // distance-1 register prefetch
                wf0[nxt] = *(const bf16x8*)(w0p + (kk + 1) * 512);
                wf1[nxt] = *(const bf16x8*)(w1p + (kk + 1) * 512);
            }
            const int c = kk * 2 + half;
            const int slot = (c & ~7) | ((c ^ rl) & 7);   // (rl+32)&7 == rl&7
            bf16x8 af0 = *(const bf16x8*)(&As[rl * D_IN + slot * 8]);
            bf16x8 af1 = *(const bf16x8*)(&As[(rl + 32) * D_IN + slot * 8]);
            acc[0][0] = __builtin_amdgcn_mfma_f32_32x32x16_bf16(af0, wf0[cur], acc[0][0], 0, 0, 0);
            acc[0][1] = __builtin_amdgcn_mfma_f32_32x32x16_bf16(af0, wf1[cur], acc[0][1], 0, 0, 0);
            acc[1][0] = __builtin_amdgcn_mfma_f32_32x32x16_bf16(af1, wf0[cur], acc[1][0], 0, 0, 0);
            acc[1][1] = __builtin_amdgcn_mfma_f32_32x32x16_bf16(af1, wf1[cur], acc[1][1], 0, 0, 0);
        }

        // fold this pass: relu(h)+bias then dot with W2, accumulate per-lane
#pragma unroll
        for (int ti = 0; ti < 2; ++ti)
#pragma unroll
            for (int r = 0; r < 16; ++r)
                rowpart[ti][r] += fmaxf(acc[ti][0][r] + b0a, 0.f) * w2a
                                + fmaxf(acc[ti][1][r] + b0b, 0.f) * w2b;
    }

    // ---- final: shuffle-reduce over 32 col-lanes, cross-wave sum via LDS ----
    // C/D layout (m74/m101): col = lane&31, row = (r&3) + 8*(r>>2) + 4*half
#pragma unroll
    for (int ti = 0; ti < 2; ++ti)
#pragma unroll
        for (int r = 0; r < 16; ++r) {
            float p = rowpart[ti][r];
#pragma unroll
            for (int m = 1; m <= 16; m <<= 1)
                p += __shfl_xor(p, m, 64);        // stays within each 32-half
            if (rl == 0)
                red[wave][ti * 32 + (r & 3) + 8 * (r >> 2) + 4 * half] = p;
        }
    __syncthreads();
    if (tid < STRIP) {
        float s = b2[0];
#pragma unroll
        for (int w = 0; w < 8; ++w) s += red[w][tid];
        out[row0 + tid] = s;
    }
}

// ---------------- naive fallback (correctness only; ws too small) ----------------
__global__ __launch_bounds__(256) void k_naive(
    const float* __restrict__ x, const float* __restrict__ W0,
    const float* __restrict__ b0, const float* __restrict__ A,
    const float* __restrict__ Bl, const float* __restrict__ W2,
    const float* __restrict__ b2, float* __restrict__ out)
{
    __shared__ float xs[D_IN];
    int b = blockIdx.x;
    for (int d = threadIdx.x; d < D_IN; d += 256) xs[d] = x[(size_t)b * D_IN + d];
    __syncthreads();
    float part = 0.f;
    for (int m = threadIdx.x; m < M_HID; m += 256) {
        float h = b0[m];
        const float* wr = W0 + (size_t)m * D_IN;
        const float* brow = Bl + m * R_LORA;
        for (int d = 0; d < D_IN; ++d) {
            float w = wr[d];
            for (int r = 0; r < R_LORA; ++r) w += SCALING * brow[r] * A[r * D_IN + d];
            h += xs[d] * w;
        }
        part += fmaxf(h, 0.f) * W2[m];
    }
    __shared__ float sred[256];
    sred[threadIdx.x] = part;
    __syncthreads();
    for (int s = 128; s > 0; s >>= 1) {
        if (threadIdx.x < s) sred[threadIdx.x] += sred[threadIdx.x + s];
        __syncthreads();
    }
    if (threadIdx.x == 0) out[b] = sred[0] + b2[0];
}

// ---------------- host ----------------
extern "C" void kernel_launch(void* const* d_in, const int* in_sizes, int n_in,
                              void* d_out, int out_size, void* d_ws, size_t ws_size,
                              hipStream_t stream) {
    const float* x  = (const float*)d_in[0];
    const float* W0 = (const float*)d_in[1];
    const float* b0 = (const float*)d_in[2];
    const float* A  = (const float*)d_in[3];
    const float* Bl = (const float*)d_in[4];
    const float* W2 = (const float*)d_in[5];
    const float* b2 = (const float*)d_in[6];
    float* out = (float*)d_out;

    const size_t wb_bytes = (size_t)M_HID * D_IN * 2;   // 8 MiB fragment-ordered W_eff
    if (ws_size >= wb_bytes) {
        unsigned short* wb = (unsigned short*)d_ws;
        hipLaunchKernelGGL(k_wprep, dim3(M_HID * D_IN / 8 / 256), dim3(256), 0, stream,
                           W0, A, Bl, wb);
        hipLaunchKernelGGL(k_strip, dim3(BATCH / STRIP), dim3(NTHREADS), 0, stream,
                           x, wb, b0, W2, b2, out);
    } else {
        hipLaunchKernelGGL(k_naive, dim3(BATCH), dim3(256), 0, stream,
                           x, W0, b0, A, Bl, W2, b2, out);
    }
}

// Round 5
// 248.478 us; speedup vs baseline: 1.2555x; 1.0459x over previous
//
#include <hip/hip_runtime.h>
#include <hip/hip_bf16.h>
#include <stdint.h>

// Problem constants (fixed by the reference setup_inputs)
#define BATCH  16384
#define D_IN   1024
#define M_HID  4096
#define R_LORA 16
#define SCALING 2.0f   // ALPHA/R = 32/16

// Structure (R5): barrier-free K-loop (R4) + two fixes from R4 counters:
//  - wf prefetch distance 1 -> 4 (R4: per-iter 780 cyc vs 128 cyc MFMA =
//    latency-underhidden wb stream through L2/L3; 8 loads in flight now)
//  - x strip stored chunk-major As[c][row][8] so hot-loop ds_read_b128 is
//    wave-contiguous 1 KiB -> 0 bank conflicts (R4: 4 extra cyc/read from
//    residual 4-way aliasing of the xor swizzle)
#define STRIP    64
#define NTHREADS 512

typedef __bf16 bf16x8 __attribute__((ext_vector_type(8)));
typedef float  f32x16 __attribute__((ext_vector_type(16)));

__device__ __forceinline__ unsigned short f2bf(float f) {
    union { float f; unsigned int u; } c; c.f = f;
    unsigned int u = c.u;
    return (unsigned short)((u + 0x7FFFu + ((u >> 16) & 1u)) >> 16);
}

// ---------------- prep: W_eff -> fragment-ordered bf16 ----------------
// Short-offset n32*32768 + c*256 + rl*8 holds W_eff[n32*32+rl][c*8 .. c*8+8).
// A wave's B-fragment read is one contiguous 1 KiB global load.
__global__ __launch_bounds__(256) void k_wprep(
    const float* __restrict__ W0, const float* __restrict__ A,
    const float* __restrict__ Bl, unsigned short* __restrict__ wb)
{
    int id = blockIdx.x * 256 + threadIdx.x;        // 524288 total
    int rl  = id & 31;
    int c   = (id >> 5) & 127;
    int n32 = id >> 12;
    int n = n32 * 32 + rl, k0 = c * 8;
    const float* wr = W0 + (size_t)n * D_IN + k0;
    float4 v0 = *(const float4*)(wr);
    float4 v1 = *(const float4*)(wr + 4);
    const float* brow = Bl + n * R_LORA;
#pragma unroll
    for (int r = 0; r < R_LORA; ++r) {
        float s = SCALING * brow[r];
        const float* ar = A + r * D_IN + k0;
        float4 a0 = *(const float4*)(ar);
        float4 a1 = *(const float4*)(ar + 4);
        v0.x += s * a0.x; v0.y += s * a0.y; v0.z += s * a0.z; v0.w += s * a0.w;
        v1.x += s * a1.x; v1.y += s * a1.y; v1.z += s * a1.z; v1.w += s * a1.w;
    }
    uint4 o;
    o.x = (unsigned)f2bf(v0.x) | ((unsigned)f2bf(v0.y) << 16);
    o.y = (unsigned)f2bf(v0.z) | ((unsigned)f2bf(v0.w) << 16);
    o.z = (unsigned)f2bf(v1.x) | ((unsigned)f2bf(v1.y) << 16);
    o.w = (unsigned)f2bf(v1.z) | ((unsigned)f2bf(v1.w) << 16);
    ((uint4*)wb)[id] = o;
}

// ---------------- main fused kernel ----------------
__global__ __launch_bounds__(NTHREADS, 2) void k_strip(
    const float* __restrict__ xf, const unsigned short* __restrict__ wb,
    const float* __restrict__ b0, const float* __restrict__ W2,
    const float* __restrict__ b2, float* __restrict__ out)
{
    // x strip, chunk-major: As[c*512 + r*8 + j] = x_bf16[row0+r][c*8+j]
    __shared__ unsigned short As[STRIP * D_IN];   // 128 KiB
    __shared__ float red[8][STRIP];               // 2 KiB cross-wave reduce

    const int tid  = threadIdx.x;
    const int lane = tid & 63;
    const int wave = tid >> 6;
    const int rl   = lane & 31;
    const int half = lane >> 5;
    const int row0 = blockIdx.x * STRIP;

    // ---- phase 1: x fp32 -> bf16 into resident LDS strip (coalesced reads;
    //      8-way LDS write conflicts are one-time, off the critical path) ----
    {
        const int r  = tid >> 3;                  // 0..63
        const int c0 = tid & 7;
        const float* xr = xf + (size_t)(row0 + r) * D_IN;
#pragma unroll
        for (int i = 0; i < 16; ++i) {
            int c = i * 8 + c0;
            float4 v0 = *(const float4*)(xr + c * 8);
            float4 v1 = *(const float4*)(xr + c * 8 + 4);
            uint4 o;
            o.x = (unsigned)f2bf(v0.x) | ((unsigned)f2bf(v0.y) << 16);
            o.y = (unsigned)f2bf(v0.z) | ((unsigned)f2bf(v0.w) << 16);
            o.z = (unsigned)f2bf(v1.x) | ((unsigned)f2bf(v1.y) << 16);
            o.w = (unsigned)f2bf(v1.z) | ((unsigned)f2bf(v1.w) << 16);
            *(uint4*)(&As[c * 512 + r * 8]) = o;
        }
    }
    __syncthreads();   // the only barrier before the final reduce

    float rowpart[2][16];
#pragma unroll
    for (int ti = 0; ti < 2; ++ti)
#pragma unroll
        for (int r = 0; r < 16; ++r) rowpart[ti][r] = 0.f;

    // ---- main: 8 passes x (K-loop with zero barriers) ----
    for (int pass = 0; pass < 8; ++pass) {
        const int n0 = wave * 64 + pass * 512;
        const float w2a = W2[n0 + rl],      b0a = b0[n0 + rl];
        const float w2b = W2[n0 + 32 + rl], b0b = b0[n0 + 32 + rl];
        const int n32 = wave * 2 + pass * 16;
        const unsigned short* w0p = wb + (size_t)n32 * 32768 + half * 256 + rl * 8;
        const unsigned short* w1p = w0p + 32768;

        f32x16 acc[2][2] = {};
        bf16x8 wf0[4], wf1[4];
#pragma unroll
        for (int p = 0; p < 4; ++p) {             // distance-4 register prefetch
            wf0[p] = *(const bf16x8*)(w0p + p * 512);
            wf1[p] = *(const bf16x8*)(w1p + p * 512);
        }

#pragma unroll 4
        for (int kk = 0; kk < 64; ++kk) {
            const int cur = kk & 3;
            const int coff = (kk * 2 + half) * 512 + rl * 8;
            bf16x8 af0 = *(const bf16x8*)(&As[coff]);        // rows 0..31
            bf16x8 af1 = *(const bf16x8*)(&As[coff + 256]);  // rows 32..63
            bf16x8 w0c = wf0[cur], w1c = wf1[cur];
            if (kk < 60) {
                wf0[cur] = *(const bf16x8*)(w0p + (kk + 4) * 512);
                wf1[cur] = *(const bf16x8*)(w1p + (kk + 4) * 512);
            }
            acc[0][0] = __builtin_amdgcn_mfma_f32_32x32x16_bf16(af0, w0c, acc[0][0], 0, 0, 0);
            acc[0][1] = __builtin_amdgcn_mfma_f32_32x32x16_bf16(af0, w1c, acc[0][1], 0, 0, 0);
            acc[1][0] = __builtin_amdgcn_mfma_f32_32x32x16_bf16(af1, w0c, acc[1][0], 0, 0, 0);
            acc[1][1] = __builtin_amdgcn_mfma_f32_32x32x16_bf16(af1, w1c, acc[1][1], 0, 0, 0);
        }

        // fold this pass: relu(h + bias) dot W2, accumulate per-lane
#pragma unroll
        for (int ti = 0; ti < 2; ++ti)
#pragma unroll
            for (int r = 0; r < 16; ++r)
                rowpart[ti][r] += fmaxf(acc[ti][0][r] + b0a, 0.f) * w2a
                                + fmaxf(acc[ti][1][r] + b0b, 0.f) * w2b;
    }

    // ---- final: shuffle-reduce over 32 col-lanes, cross-wave sum via LDS ----
    // C/D layout (m74/m101): col = lane&31, row = (r&3) + 8*(r>>2) + 4*half
#pragma unroll
    for (int ti = 0; ti < 2; ++ti)
#pragma unroll
        for (int r = 0; r < 16; ++r) {
            float p = rowpart[ti][r];
#pragma unroll
            for (int m = 1; m <= 16; m <<= 1)
                p += __shfl_xor(p, m, 64);        // stays within each 32-half
            if (rl == 0)
                red[wave][ti * 32 + (r & 3) + 8 * (r >> 2) + 4 * half] = p;
        }
    __syncthreads();
    if (tid < STRIP) {
        float s = b2[0];
#pragma unroll
        for (int w = 0; w < 8; ++w) s += red[w][tid];
        out[row0 + tid] = s;
    }
}

// ---------------- naive fallback (correctness only; ws too small) ----------------
__global__ __launch_bounds__(256) void k_naive(
    const float* __restrict__ x, const float* __restrict__ W0,
    const float* __restrict__ b0, const float* __restrict__ A,
    const float* __restrict__ Bl, const float* __restrict__ W2,
    const float* __restrict__ b2, float* __restrict__ out)
{
    __shared__ float xs[D_IN];
    int b = blockIdx.x;
    for (int d = threadIdx.x; d < D_IN; d += 256) xs[d] = x[(size_t)b * D_IN + d];
    __syncthreads();
    float part = 0.f;
    for (int m = threadIdx.x; m < M_HID; m += 256) {
        float h = b0[m];
        const float* wr = W0 + (size_t)m * D_IN;
        const float* brow = Bl + m * R_LORA;
        for (int d = 0; d < D_IN; ++d) {
            float w = wr[d];
            for (int r = 0; r < R_LORA; ++r) w += SCALING * brow[r] * A[r * D_IN + d];
            h += xs[d] * w;
        }
        part += fmaxf(h, 0.f) * W2[m];
    }
    __shared__ float sred[256];
    sred[threadIdx.x] = part;
    __syncthreads();
    for (int s = 128; s > 0; s >>= 1) {
        if (threadIdx.x < s) sred[threadIdx.x] += sred[threadIdx.x + s];
        __syncthreads();
    }
    if (threadIdx.x == 0) out[b] = sred[0] + b2[0];
}

// ---------------- host ----------------
extern "C" void kernel_launch(void* const* d_in, const int* in_sizes, int n_in,
                              void* d_out, int out_size, void* d_ws, size_t ws_size,
                              hipStream_t stream) {
    const float* x  = (const float*)d_in[0];
    const float* W0 = (const float*)d_in[1];
    const float* b0 = (const float*)d_in[2];
    const float* A  = (const float*)d_in[3];
    const float* Bl = (const float*)d_in[4];
    const float* W2 = (const float*)d_in[5];
    const float* b2 = (const float*)d_in[6];
    float* out = (float*)d_out;

    const size_t wb_bytes = (size_t)M_HID * D_IN * 2;   // 8 MiB fragment-ordered W_eff
    if (ws_size >= wb_bytes) {
        unsigned short* wb = (unsigned short*)d_ws;
        hipLaunchKernelGGL(k_wprep, dim3(M_HID * D_IN / 8 / 256), dim3(256), 0, stream,
                           W0, A, Bl, wb);
        hipLaunchKernelGGL(k_strip, dim3(BATCH / STRIP), dim3(NTHREADS), 0, stream,
                           x, wb, b0, W2, b2, out);
    } else {
        hipLaunchKernelGGL(k_naive, dim3(BATCH), dim3(256), 0, stream,
                           x, W0, b0, A, Bl, W2, b2, out);
    }
}